// Round 10
// baseline (238.357 us; speedup 1.0000x reference)
//
#include <hip/hip_runtime.h>

// Problem constants (fixed by setup_inputs)
#define B_   8
#define C_   64
#define O_   64
#define H_   128
#define W_   128
#define HO_  128
#define WO_  128
#define K2_  9
#define MOFF 18          // 2*K*K offset channels
#define PLANE (H_*W_)    // 16384
#define KTOT 576         // C_*K2_
#define NT   64          // pixels per block tile

typedef short bf16x8 __attribute__((ext_vector_type(8)));
typedef float f32x16 __attribute__((ext_vector_type(16)));

__device__ __forceinline__ unsigned short f2bf(float f) {
    // round-to-nearest-even fp32 -> bf16
    unsigned u = __float_as_uint(f);
    u += 0x7fff + ((u >> 16) & 1);
    return (unsigned short)(u >> 16);
}
__device__ __forceinline__ float bf2f(short v) {
    return __uint_as_float(((unsigned)(unsigned short)v) << 16);
}

// ---------------------------------------------------------------------------
// cvt_w: main-conv weights -> bf16 rows [o][576] in TAP-MAJOR chunk order:
//   pos = cc*144 + t*16 + cl   <->   w[o][c = cc*16+cl][tap t]
// ---------------------------------------------------------------------------
__global__ __launch_bounds__(256) void cvt_w_kernel(const float* __restrict__ w,
                                                    unsigned short* __restrict__ wbf) {
    int i = blockIdx.x * 256 + threadIdx.x;     // 64*576 = 36864
    if (i >= O_ * KTOT) return;
    int o = i / KTOT, pos = i % KTOT;
    int cc = pos / 144, r = pos % 144, t = r / 16, cl = r % 16;
    wbf[i] = f2bf(w[o * KTOT + (cc * 16 + cl) * 9 + t]);
}

// cvt_woff: offset-conv weights, same TAP-MAJOR order, 32 rows (o>=18 zero).
__global__ __launch_bounds__(256) void cvt_woff_kernel(const float* __restrict__ w_off,
                                                       unsigned short* __restrict__ wobf) {
    int i = blockIdx.x * 256 + threadIdx.x;     // 32*576 = 18432
    if (i >= 32 * KTOT) return;
    int o = i / KTOT, pos = i % KTOT;
    int cc = pos / 144, r = pos % 144, t = r / 16, cl = r % 16;
    wobf[i] = (o < MOFF) ? f2bf(w_off[o * KTOT + (cc * 16 + cl) * 9 + t])
                         : (unsigned short)0;
}

// ---------------------------------------------------------------------------
// Chunk-major NHWC bf16 transpose:
//   xt[((cc*B + b)*PLANE + y*W + px)*16 + cl] = bf16(x[((b*64 + cc*16+cl)*H+y)*W+px])
// ---------------------------------------------------------------------------
__global__ __launch_bounds__(256) void nhwc_kernel(const float* __restrict__ x,
                                                   unsigned short* __restrict__ xt) {
    __shared__ unsigned short T[64 * 130];      // stride 130 (odd 16B groups)
    const int tid = threadIdx.x;
    const int b = blockIdx.x & 7;
    const int y = blockIdx.x >> 3;
    const float* src = x + (size_t)b * C_ * PLANE + y * W_;
    for (int i = tid; i < 64 * 128; i += 256) {
        int c = i >> 7, px = i & 127;
        T[c * 130 + px] = f2bf(src[c * PLANE + px]);
    }
    __syncthreads();
    for (int j = tid; j < 128 * 4; j += 256) {
        int cc = j >> 7, px = j & 127;
        unsigned short* dst = xt + ((size_t)(cc * B_ + b) * PLANE + y * W_ + px) * 16;
        ushort4 v0 = { T[(cc*16+ 0)*130+px], T[(cc*16+ 1)*130+px],
                       T[(cc*16+ 2)*130+px], T[(cc*16+ 3)*130+px] };
        ushort4 v1 = { T[(cc*16+ 4)*130+px], T[(cc*16+ 5)*130+px],
                       T[(cc*16+ 6)*130+px], T[(cc*16+ 7)*130+px] };
        ushort4 v2 = { T[(cc*16+ 8)*130+px], T[(cc*16+ 9)*130+px],
                       T[(cc*16+10)*130+px], T[(cc*16+11)*130+px] };
        ushort4 v3 = { T[(cc*16+12)*130+px], T[(cc*16+13)*130+px],
                       T[(cc*16+14)*130+px], T[(cc*16+15)*130+px] };
        *(ushort4*)(dst)      = v0;
        *(ushort4*)(dst + 4)  = v1;
        *(ushort4*)(dst + 8)  = v2;
        *(ushort4*)(dst + 12) = v3;
    }
}

// ---------------------------------------------------------------------------
// FUSED offset-conv + deformable-conv. Block = 64-px tile of one (b,ho) row.
// ls is GRANULE-MAJOR: granule g = 2*t + half (16 B = 8 bf16 of pos t*16+cl),
//   ls[(g*NT + p)*8 + j]. Sampler writes (lanes=p, contiguous) and MFMA reads
//   (lanes=m, contiguous 512 B per half-wave) are both conflict-free.
// Phase A: offset conv M=32 x N=64; all waves sample, waves 0/1 MFMA -> lo.
// Phase B: deform conv M=64 x N=64; 2x2 wave tiling, one acc per wave.
// LDS: 18,432 (ls) + 4,608 (lo) = 23,040 B -> 5+ blocks/CU.
// ---------------------------------------------------------------------------
__global__ __launch_bounds__(256, 5) void fused_kernel(const unsigned short* __restrict__ xt,
        const unsigned short* __restrict__ wobf, const float* __restrict__ b_off,
        const unsigned short* __restrict__ wbf, const float* __restrict__ bias,
        float* __restrict__ out) {
    __shared__ __align__(16) unsigned short ls[18 * NT * 8];    // 18,432 B
    __shared__ float lo[MOFF * NT];                             //  4,608 B
    const int tid = threadIdx.x;
    const int id  = blockIdx.x;                 // 2048
    const int b    = id & 7;                    // batch-per-XCD heuristic
    const int half = (id >> 3) & 1;
    const int ho   = id >> 4;
    const int p    = tid & 63;                  // pixel within tile
    const int wo   = (half << 6) + p;           // global wo
    const int gq   = tid >> 6;                  // tap-group == wave id
    const int lane = tid & 63;
    const int wv   = tid >> 6;
    const int m    = lane & 31;
    const int kh   = lane >> 5;

    // ================= Phase A: offset conv (M=32, N=64) =================
    {
        const int nbase = (wv & 1) << 5;        // used only when wv < 2
        f32x16 acc = {};
        for (int cc = 0; cc < 4; ++cc) {
            __syncthreads();                    // prev MFMA done with ls
            const unsigned short* xtc = xt + (size_t)(cc * B_ + b) * PLANE * 16;
            bf16x8 af[9];
            if (wv < 2) {
                #pragma unroll
                for (int ks = 0; ks < 9; ++ks)
                    af[ks] = *(const bf16x8*)&wobf[m * KTOT + cc * 144 + ks * 16 + kh * 8];
            }
            // sampling: taps 2*gq, 2*gq+1 (all waves) + tap 8 (wave 0)
            #pragma unroll
            for (int i = 0; i < 3; ++i) {
                if (i == 2 && gq != 0) break;   // wave-uniform
                const int t = (i < 2) ? (gq * 2 + i) : 8;
                const int y  = ho - 1 + t / 3;
                const int xx = wo - 1 + t % 3;
                const bool ok = ((unsigned)y < (unsigned)H_) && ((unsigned)xx < (unsigned)W_);
                bf16x8 v0 = {}, v1 = {};
                if (ok) {
                    const unsigned short* rp = xtc + (y * W_ + xx) * 16;
                    v0 = *(const bf16x8*)rp;
                    v1 = *(const bf16x8*)(rp + 8);
                }
                *(bf16x8*)&ls[((2 * t)     * NT + p) * 8] = v0;
                *(bf16x8*)&ls[((2 * t + 1) * NT + p) * 8] = v1;
            }
            __syncthreads();                    // ls ready
            if (wv < 2) {
                #pragma unroll
                for (int ks = 0; ks < 9; ++ks) {
                    bf16x8 s = *(const bf16x8*)&ls[((2 * ks + kh) * NT + nbase + m) * 8];
                    acc = __builtin_amdgcn_mfma_f32_32x32x16_bf16(af[ks], s, acc, 0, 0, 0);
                }
            }
        }
        if (wv < 2) {                           // epilogue -> LDS lo
            #pragma unroll
            for (int r = 0; r < 16; ++r) {
                int mo = (r & 3) + ((r >> 2) << 3) + (kh << 2);
                if (mo < MOFF) lo[mo * NT + nbase + m] = acc[r] + b_off[mo];
            }
        }
    }
    __syncthreads();                            // lo ready for phase B

    // ================= Phase B: deformable conv (M=64, N=64) =============
    const int mbase = (wv & 1) << 5;
    const int nbase = (wv >> 1) << 5;

    // ---- bilinear setup for this thread's taps (slot 2 = tap 8, wave 0) ----
    int   addr[3][4];
    float cwt[3][4];
    #pragma unroll
    for (int i = 0; i < 3; ++i) {
        const int t = (i < 2) ? (gq * 2 + i) : 8;
        float dy = lo[(2 * t) * NT + p];
        float dx = lo[(2 * t + 1) * NT + p];
        float py = (float)(ho - 1 + t / 3) + dy;
        float px = (float)(wo - 1 + t % 3) + dx;
        float fy = floorf(py), fx = floorf(px);
        float wy = py - fy,    wx = px - fx;
        int y0 = (int)fy, x0 = (int)fx;
        float wgt[4] = { (1.f - wy) * (1.f - wx), (1.f - wy) * wx,
                         wy * (1.f - wx),         wy * wx };
        #pragma unroll
        for (int c2 = 0; c2 < 4; ++c2) {
            int yy = y0 + (c2 >> 1);
            int xx = x0 + (c2 & 1);
            bool valid = ((unsigned)yy < (unsigned)H_) && ((unsigned)xx < (unsigned)W_);
            int yc = min(max(yy, 0), H_ - 1);
            int xc = min(max(xx, 0), W_ - 1);
            addr[i][c2] = yc * W_ + xc;
            cwt[i][c2]  = valid ? wgt[c2] : 0.f;
        }
    }

    f32x16 acc = {};
    for (int cc = 0; cc < 4; ++cc) {
        __syncthreads();                        // prev MFMA (or phase A) done with ls
        const unsigned short* xtc = xt + (size_t)(cc * B_ + b) * PLANE * 16;
        bf16x8 af[9];
        #pragma unroll
        for (int ks = 0; ks < 9; ++ks)
            af[ks] = *(const bf16x8*)&wbf[(mbase + m) * KTOT + cc * 144 + ks * 16 + kh * 8];
        // sampling: this thread's taps; per tap 4 corners x 32 contiguous bytes
        #pragma unroll
        for (int i = 0; i < 3; ++i) {
            if (i == 2 && gq != 0) break;       // wave-uniform
            const int t = (i < 2) ? (gq * 2 + i) : 8;
            float s[16];
            #pragma unroll
            for (int j = 0; j < 16; ++j) s[j] = 0.f;
            #pragma unroll
            for (int c2 = 0; c2 < 4; ++c2) {
                const unsigned short* rp = xtc + addr[i][c2] * 16;
                bf16x8 u0 = *(const bf16x8*)rp;
                bf16x8 u1 = *(const bf16x8*)(rp + 8);
                float wgt = cwt[i][c2];
                #pragma unroll
                for (int j = 0; j < 8; ++j) {
                    s[j]     += wgt * bf2f(u0[j]);
                    s[8 + j] += wgt * bf2f(u1[j]);
                }
            }
            bf16x8 v0, v1;
            #pragma unroll
            for (int j = 0; j < 8; ++j) {
                v0[j] = (short)f2bf(s[j]);
                v1[j] = (short)f2bf(s[8 + j]);
            }
            *(bf16x8*)&ls[((2 * t)     * NT + p) * 8] = v0;
            *(bf16x8*)&ls[((2 * t + 1) * NT + p) * 8] = v1;
        }
        __syncthreads();                        // ls ready
        #pragma unroll
        for (int ks = 0; ks < 9; ++ks) {
            bf16x8 s = *(const bf16x8*)&ls[((2 * ks + kh) * NT + nbase + m) * 8];
            acc = __builtin_amdgcn_mfma_f32_32x32x16_bf16(af[ks], s, acc, 0, 0, 0);
        }
    }

    // epilogue: D col = pixel (nbase+m), row = out channel
    {
        float* op = out + (size_t)b * O_ * PLANE + ho * WO_ + (half << 6) + nbase + m;
        #pragma unroll
        for (int r = 0; r < 16; ++r) {
            int mo = mbase + (r & 3) + ((r >> 2) << 3) + (kh << 2);
            __builtin_nontemporal_store(acc[r] + bias[mo], op + (size_t)mo * PLANE);
        }
    }
}

// ---------------------------------------------------------------------------
extern "C" void kernel_launch(void* const* d_in, const int* in_sizes, int n_in,
                              void* d_out, int out_size, void* d_ws, size_t ws_size,
                              hipStream_t stream) {
    const float* x     = (const float*)d_in[0];
    const float* w_off = (const float*)d_in[1];
    const float* b_off = (const float*)d_in[2];
    const float* w     = (const float*)d_in[3];
    const float* bias  = (const float*)d_in[4];
    float* out = (float*)d_out;

    unsigned short* wbf  = (unsigned short*)d_ws;                   // 72 KB (tap-major)
    unsigned short* wobf = wbf + O_ * KTOT;                         // 36 KB (tap-major)
    unsigned short* xt   = wobf + 32 * KTOT;                        // 16.78 MB chunk-major

    cvt_w_kernel   <<<(O_ * KTOT + 255) / 256, 256, 0, stream>>>(w, wbf);
    cvt_woff_kernel<<<(32 * KTOT + 255) / 256, 256, 0, stream>>>(w_off, wobf);
    nhwc_kernel    <<<B_ * H_, 256, 0, stream>>>(x, xt);
    fused_kernel   <<<B_ * HO_ * 2, 256, 0, stream>>>(xt, wobf, b_off, wbf, bias, out);
}

// Round 11
// 223.348 us; speedup vs baseline: 1.0672x; 1.0672x over previous
//
#include <hip/hip_runtime.h>

// Problem constants (fixed by setup_inputs)
#define B_   8
#define C_   64
#define O_   64
#define H_   128
#define W_   128
#define HO_  128
#define WO_  128
#define K2_  9
#define MOFF 18          // 2*K*K offset channels
#define PLANE (H_*W_)    // 16384
#define KTOT 576         // C_*K2_
// LDS row stride in bf16 units: 304 B = 19 x 16B groups. Group stride 19 mod 32
// (odd) -> b128 ops across consecutive rows are conflict-free.
#define LSTRIDE 152

typedef short bf16x8 __attribute__((ext_vector_type(8)));
typedef float f32x16 __attribute__((ext_vector_type(16)));

__device__ __forceinline__ unsigned short f2bf(float f) {
    // round-to-nearest-even fp32 -> bf16
    unsigned u = __float_as_uint(f);
    u += 0x7fff + ((u >> 16) & 1);
    return (unsigned short)(u >> 16);
}
__device__ __forceinline__ float bf2f(short v) {
    return __uint_as_float(((unsigned)(unsigned short)v) << 16);
}

// ---------------------------------------------------------------------------
// cvt_w: main-conv weights -> bf16 rows [o][576] in TAP-MAJOR chunk order:
//   pos = cc*144 + t*16 + cl   <->   w[o][c = cc*16+cl][tap t]
// ---------------------------------------------------------------------------
__global__ __launch_bounds__(256) void cvt_w_kernel(const float* __restrict__ w,
                                                    unsigned short* __restrict__ wbf) {
    int i = blockIdx.x * 256 + threadIdx.x;     // 64*576 = 36864
    if (i >= O_ * KTOT) return;
    int o = i / KTOT, pos = i % KTOT;
    int cc = pos / 144, r = pos % 144, t = r / 16, cl = r % 16;
    wbf[i] = f2bf(w[o * KTOT + (cc * 16 + cl) * 9 + t]);
}

// cvt_woff: offset-conv weights, same TAP-MAJOR order, 32 rows (o>=18 zero).
__global__ __launch_bounds__(256) void cvt_woff_kernel(const float* __restrict__ w_off,
                                                       unsigned short* __restrict__ wobf) {
    int i = blockIdx.x * 256 + threadIdx.x;     // 32*576 = 18432
    if (i >= 32 * KTOT) return;
    int o = i / KTOT, pos = i % KTOT;
    int cc = pos / 144, r = pos % 144, t = r / 16, cl = r % 16;
    wobf[i] = (o < MOFF) ? f2bf(w_off[o * KTOT + (cc * 16 + cl) * 9 + t])
                         : (unsigned short)0;
}

// ---------------------------------------------------------------------------
// Chunk-major NHWC bf16 transpose:
//   xt[((cc*B + b)*PLANE + y*W + px)*16 + cl] = bf16(x[((b*64 + cc*16+cl)*H+y)*W+px])
// ---------------------------------------------------------------------------
__global__ __launch_bounds__(256) void nhwc_kernel(const float* __restrict__ x,
                                                   unsigned short* __restrict__ xt) {
    __shared__ unsigned short T[64 * 130];      // stride 130 (odd 16B groups)
    const int tid = threadIdx.x;
    const int b = blockIdx.x & 7;
    const int y = blockIdx.x >> 3;
    const float* src = x + (size_t)b * C_ * PLANE + y * W_;
    for (int i = tid; i < 64 * 128; i += 256) {
        int c = i >> 7, px = i & 127;
        T[c * 130 + px] = f2bf(src[c * PLANE + px]);
    }
    __syncthreads();
    for (int j = tid; j < 128 * 4; j += 256) {
        int cc = j >> 7, px = j & 127;
        unsigned short* dst = xt + ((size_t)(cc * B_ + b) * PLANE + y * W_ + px) * 16;
        ushort4 v0 = { T[(cc*16+ 0)*130+px], T[(cc*16+ 1)*130+px],
                       T[(cc*16+ 2)*130+px], T[(cc*16+ 3)*130+px] };
        ushort4 v1 = { T[(cc*16+ 4)*130+px], T[(cc*16+ 5)*130+px],
                       T[(cc*16+ 6)*130+px], T[(cc*16+ 7)*130+px] };
        ushort4 v2 = { T[(cc*16+ 8)*130+px], T[(cc*16+ 9)*130+px],
                       T[(cc*16+10)*130+px], T[(cc*16+11)*130+px] };
        ushort4 v3 = { T[(cc*16+12)*130+px], T[(cc*16+13)*130+px],
                       T[(cc*16+14)*130+px], T[(cc*16+15)*130+px] };
        *(ushort4*)(dst)      = v0;
        *(ushort4*)(dst + 4)  = v1;
        *(ushort4*)(dst + 8)  = v2;
        *(ushort4*)(dst + 12) = v3;
    }
}

// ---------------------------------------------------------------------------
// FUSED offset-conv + deformable-conv (R9 structure, LDS-aliased lo).
// Block = (b,ho), 256 threads = 4 waves, N=128 pixels.
// lo (offsets, 18x128 fp32 = 9,216 B) ALIASES the first quarter of ls:
//   phase A: ... last MFMA reads ls -> barrier -> epilogue writes lo
//   phase B: setup reads lo into regs -> loop-top barrier -> sampling
//            overwrites ls (incl. lo region). All hazards barrier-separated.
// LDS total = 38,912 B -> 4 blocks/CU (grid 1024 = exactly 4/CU).
// ---------------------------------------------------------------------------
__global__ __launch_bounds__(256, 4) void fused_kernel(const unsigned short* __restrict__ xt,
        const unsigned short* __restrict__ wobf, const float* __restrict__ b_off,
        const unsigned short* __restrict__ wbf, const float* __restrict__ bias,
        float* __restrict__ out) {
    __shared__ __align__(16) unsigned short ls[128 * LSTRIDE];  // 38,912 B
    float* lo = (float*)ls;                     // aliased: first 9,216 B
    const int tid = threadIdx.x;
    const int id  = blockIdx.x;                 // 1024
    const int b   = id & 7;                     // batch-per-XCD heuristic
    const int ho  = id >> 3;
    const int p   = tid & 127;                  // pixel = wo
    const int gh  = tid >> 7;                   // tap group: 0 -> 0..4, 1 -> 4..8
    const int t0  = gh << 2;                    // 0 or 4
    const int lane  = tid & 63;
    const int wv    = tid >> 6;
    const int m     = lane & 31;
    const int kh    = lane >> 5;

    // ================= Phase A: offset conv (M=32, N=128) =================
    {
        const int nbase = wv << 5;
        f32x16 acc = {};
        for (int cc = 0; cc < 4; ++cc) {
            __syncthreads();                    // prev MFMA done with ls
            const unsigned short* xtc = xt + (size_t)(cc * B_ + b) * PLANE * 16;
            bf16x8 af[9];
            #pragma unroll
            for (int ks = 0; ks < 9; ++ks)
                af[ks] = *(const bf16x8*)&wobf[m * KTOT + cc * 144 + ks * 16 + kh * 8];
            #pragma unroll
            for (int i = 0; i < 5; ++i) {
                const int t = t0 + i;
                const int y  = ho - 1 + t / 3;
                const int xx = p  - 1 + t % 3;
                const bool ok = ((unsigned)y < (unsigned)H_) && ((unsigned)xx < (unsigned)W_);
                bf16x8 v0 = {}, v1 = {};
                if (ok) {
                    const unsigned short* rp = xtc + (y * W_ + xx) * 16;
                    v0 = *(const bf16x8*)rp;
                    v1 = *(const bf16x8*)(rp + 8);
                }
                *(bf16x8*)&ls[p * LSTRIDE + t * 16]     = v0;
                *(bf16x8*)&ls[p * LSTRIDE + t * 16 + 8] = v1;
            }
            __syncthreads();                    // ls ready
            #pragma unroll
            for (int ks = 0; ks < 9; ++ks) {
                bf16x8 s = *(const bf16x8*)&ls[(nbase + m) * LSTRIDE + ks * 16 + kh * 8];
                acc = __builtin_amdgcn_mfma_f32_32x32x16_bf16(af[ks], s, acc, 0, 0, 0);
            }
        }
        __syncthreads();                        // all MFMA reads of ls done (lo aliases ls)
        // epilogue -> LDS (D col = pixel nbase+m, row = offset channel)
        #pragma unroll
        for (int r = 0; r < 16; ++r) {
            int mo = (r & 3) + ((r >> 2) << 3) + (kh << 2);
            if (mo < MOFF) lo[mo * 128 + nbase + m] = acc[r] + b_off[mo];
        }
    }
    __syncthreads();                            // lo ready for phase B

    // ================= Phase B: deformable conv (M=64, N=128) =============
    const int mbase = (wv & 1) << 5;
    const int nb0   = (wv >> 1) << 6;           // 0 or 64

    // ---- per-(pixel, tap-subset) bilinear setup from lo (into registers) ----
    int   addr[5][4];                           // pixel index (y*W+x), clamped
    float cwt[5][4];                            // masked corner weights
    #pragma unroll
    for (int i = 0; i < 5; ++i) {
        int t = t0 + i;
        float dy = lo[(2 * t) * 128 + p];
        float dx = lo[(2 * t + 1) * 128 + p];
        float py = (float)(ho - 1 + t / 3) + dy;
        float px = (float)(p  - 1 + t % 3) + dx;
        float fy = floorf(py), fx = floorf(px);
        float wy = py - fy,    wx = px - fx;
        int y0 = (int)fy, x0 = (int)fx;
        float wgt[4] = { (1.f - wy) * (1.f - wx), (1.f - wy) * wx,
                         wy * (1.f - wx),         wy * wx };
        #pragma unroll
        for (int c2 = 0; c2 < 4; ++c2) {
            int yy = y0 + (c2 >> 1);
            int xx = x0 + (c2 & 1);
            bool valid = ((unsigned)yy < (unsigned)H_) && ((unsigned)xx < (unsigned)W_);
            int yc = min(max(yy, 0), H_ - 1);
            int xc = min(max(xx, 0), W_ - 1);
            addr[i][c2] = yc * W_ + xc;
            cwt[i][c2]  = valid ? wgt[c2] : 0.f;
        }
    }

    f32x16 acc[2] = {};
    for (int cc = 0; cc < 4; ++cc) {
        __syncthreads();                        // lo reads done / prev MFMA done with ls
        const unsigned short* xtc = xt + (size_t)(cc * B_ + b) * PLANE * 16;
        bf16x8 af[9];
        #pragma unroll
        for (int ks = 0; ks < 9; ++ks)
            af[ks] = *(const bf16x8*)&wbf[(mbase + m) * KTOT + cc * 144 + ks * 16 + kh * 8];
        // sampling: 5 taps; per tap 4 corners x 32 contiguous bytes
        #pragma unroll
        for (int i = 0; i < 5; ++i) {
            float s[16];
            #pragma unroll
            for (int j = 0; j < 16; ++j) s[j] = 0.f;
            #pragma unroll
            for (int c2 = 0; c2 < 4; ++c2) {
                const unsigned short* rp = xtc + addr[i][c2] * 16;
                bf16x8 u0 = *(const bf16x8*)rp;
                bf16x8 u1 = *(const bf16x8*)(rp + 8);
                float wgt = cwt[i][c2];
                #pragma unroll
                for (int j = 0; j < 8; ++j) {
                    s[j]     += wgt * bf2f(u0[j]);
                    s[8 + j] += wgt * bf2f(u1[j]);
                }
            }
            bf16x8 v0, v1;
            #pragma unroll
            for (int j = 0; j < 8; ++j) {
                v0[j] = (short)f2bf(s[j]);
                v1[j] = (short)f2bf(s[8 + j]);
            }
            int t = t0 + i;
            *(bf16x8*)&ls[p * LSTRIDE + t * 16]     = v0;
            *(bf16x8*)&ls[p * LSTRIDE + t * 16 + 8] = v1;
        }
        __syncthreads();                        // ls ready
        #pragma unroll
        for (int ks = 0; ks < 9; ++ks) {
            bf16x8 s0 = *(const bf16x8*)&ls[(nb0 + m) * LSTRIDE + ks * 16 + kh * 8];
            bf16x8 s1 = *(const bf16x8*)&ls[(nb0 + 32 + m) * LSTRIDE + ks * 16 + kh * 8];
            acc[0] = __builtin_amdgcn_mfma_f32_32x32x16_bf16(af[ks], s0, acc[0], 0, 0, 0);
            acc[1] = __builtin_amdgcn_mfma_f32_32x32x16_bf16(af[ks], s1, acc[1], 0, 0, 0);
        }
    }

    // epilogue: D col = pixel, row = out channel
    #pragma unroll
    for (int nt = 0; nt < 2; ++nt) {
        int col = nb0 + nt * 32 + m;
        float* op = out + (size_t)b * O_ * PLANE + ho * WO_ + col;
        #pragma unroll
        for (int r = 0; r < 16; ++r) {
            int mo = mbase + (r & 3) + ((r >> 2) << 3) + (kh << 2);
            __builtin_nontemporal_store(acc[nt][r] + bias[mo], op + (size_t)mo * PLANE);
        }
    }
}

// ---------------------------------------------------------------------------
extern "C" void kernel_launch(void* const* d_in, const int* in_sizes, int n_in,
                              void* d_out, int out_size, void* d_ws, size_t ws_size,
                              hipStream_t stream) {
    const float* x     = (const float*)d_in[0];
    const float* w_off = (const float*)d_in[1];
    const float* b_off = (const float*)d_in[2];
    const float* w     = (const float*)d_in[3];
    const float* bias  = (const float*)d_in[4];
    float* out = (float*)d_out;

    unsigned short* wbf  = (unsigned short*)d_ws;                   // 72 KB (tap-major)
    unsigned short* wobf = wbf + O_ * KTOT;                         // 36 KB (tap-major)
    unsigned short* xt   = wobf + 32 * KTOT;                        // 16.78 MB chunk-major

    cvt_w_kernel   <<<(O_ * KTOT + 255) / 256, 256, 0, stream>>>(w, wbf);
    cvt_woff_kernel<<<(32 * KTOT + 255) / 256, 256, 0, stream>>>(w_off, wobf);
    nhwc_kernel    <<<B_ * H_, 256, 0, stream>>>(x, xt);
    fused_kernel   <<<B_ * HO_, 256, 0, stream>>>(xt, wobf, b_off, wbf, bias, out);
}

// Round 12
// 200.394 us; speedup vs baseline: 1.1894x; 1.1145x over previous
//
#include <hip/hip_runtime.h>

// Problem constants (fixed by setup_inputs)
#define B_   8
#define C_   64
#define O_   64
#define H_   128
#define W_   128
#define HO_  128
#define WO_  128
#define K2_  9
#define MOFF 18          // 2*K*K offset channels
#define PLANE (H_*W_)    // 16384
#define KTOT 576         // C_*K2_
// LDS row stride in bf16 units: 304 B = 19 x 16B groups. Group stride 19 mod 32
// (odd) -> b128 ops across consecutive rows are conflict-free.
#define LSTRIDE 152

typedef short bf16x8 __attribute__((ext_vector_type(8)));
typedef float f32x16 __attribute__((ext_vector_type(16)));

__device__ __forceinline__ unsigned short f2bf(float f) {
    // round-to-nearest-even fp32 -> bf16
    unsigned u = __float_as_uint(f);
    u += 0x7fff + ((u >> 16) & 1);
    return (unsigned short)(u >> 16);
}
__device__ __forceinline__ float bf2f(short v) {
    return __uint_as_float(((unsigned)(unsigned short)v) << 16);
}

// ---------------------------------------------------------------------------
// cvt_w: main-conv weights -> bf16 rows [o][576] in TAP-MAJOR chunk order:
//   pos = cc*144 + t*16 + cl   <->   w[o][c = cc*16+cl][tap t]
// ---------------------------------------------------------------------------
__global__ __launch_bounds__(256) void cvt_w_kernel(const float* __restrict__ w,
                                                    unsigned short* __restrict__ wbf) {
    int i = blockIdx.x * 256 + threadIdx.x;     // 64*576 = 36864
    if (i >= O_ * KTOT) return;
    int o = i / KTOT, pos = i % KTOT;
    int cc = pos / 144, r = pos % 144, t = r / 16, cl = r % 16;
    wbf[i] = f2bf(w[o * KTOT + (cc * 16 + cl) * 9 + t]);
}

// cvt_woff: offset-conv weights, same TAP-MAJOR order, 32 rows (o>=18 zero).
__global__ __launch_bounds__(256) void cvt_woff_kernel(const float* __restrict__ w_off,
                                                       unsigned short* __restrict__ wobf) {
    int i = blockIdx.x * 256 + threadIdx.x;     // 32*576 = 18432
    if (i >= 32 * KTOT) return;
    int o = i / KTOT, pos = i % KTOT;
    int cc = pos / 144, r = pos % 144, t = r / 16, cl = r % 16;
    wobf[i] = (o < MOFF) ? f2bf(w_off[o * KTOT + (cc * 16 + cl) * 9 + t])
                         : (unsigned short)0;
}

// ---------------------------------------------------------------------------
// Chunk-major NHWC bf16 transpose:
//   xt[((cc*B + b)*PLANE + y*W + px)*16 + cl] = bf16(x[((b*64 + cc*16+cl)*H+y)*W+px])
// ---------------------------------------------------------------------------
__global__ __launch_bounds__(256) void nhwc_kernel(const float* __restrict__ x,
                                                   unsigned short* __restrict__ xt) {
    __shared__ unsigned short T[64 * 130];      // stride 130 (odd 16B groups)
    const int tid = threadIdx.x;
    const int b = blockIdx.x & 7;
    const int y = blockIdx.x >> 3;
    const float* src = x + (size_t)b * C_ * PLANE + y * W_;
    for (int i = tid; i < 64 * 128; i += 256) {
        int c = i >> 7, px = i & 127;
        T[c * 130 + px] = f2bf(src[c * PLANE + px]);
    }
    __syncthreads();
    for (int j = tid; j < 128 * 4; j += 256) {
        int cc = j >> 7, px = j & 127;
        unsigned short* dst = xt + ((size_t)(cc * B_ + b) * PLANE + y * W_ + px) * 16;
        ushort4 v0 = { T[(cc*16+ 0)*130+px], T[(cc*16+ 1)*130+px],
                       T[(cc*16+ 2)*130+px], T[(cc*16+ 3)*130+px] };
        ushort4 v1 = { T[(cc*16+ 4)*130+px], T[(cc*16+ 5)*130+px],
                       T[(cc*16+ 6)*130+px], T[(cc*16+ 7)*130+px] };
        ushort4 v2 = { T[(cc*16+ 8)*130+px], T[(cc*16+ 9)*130+px],
                       T[(cc*16+10)*130+px], T[(cc*16+11)*130+px] };
        ushort4 v3 = { T[(cc*16+12)*130+px], T[(cc*16+13)*130+px],
                       T[(cc*16+14)*130+px], T[(cc*16+15)*130+px] };
        *(ushort4*)(dst)      = v0;
        *(ushort4*)(dst + 4)  = v1;
        *(ushort4*)(dst + 8)  = v2;
        *(ushort4*)(dst + 12) = v3;
    }
}

// ---------------------------------------------------------------------------
// FUSED offset-conv + deformable-conv (R9 structure; low-register phase B).
// Block = (b,ho), 256 threads = 4 waves, N=128 pixels.
// lo (offsets, 18x128 fp32) aliases the first 9,216 B of ls (barrier-separated).
// Phase B keeps only py/px per tap in registers; corner addrs/weights are
// recomputed per chunk, and A-fragments are loaded lazily in the MFMA loop —
// targets no-spill fit at 4 blocks/CU (launch_bounds(256,4)).
// LDS total = 38,912 B -> 4 blocks/CU (grid 1024 = exactly 4/CU, no tail).
// ---------------------------------------------------------------------------
__global__ __launch_bounds__(256, 4) void fused_kernel(const unsigned short* __restrict__ xt,
        const unsigned short* __restrict__ wobf, const float* __restrict__ b_off,
        const unsigned short* __restrict__ wbf, const float* __restrict__ bias,
        float* __restrict__ out) {
    __shared__ __align__(16) unsigned short ls[128 * LSTRIDE];  // 38,912 B
    float* lo = (float*)ls;                     // aliased: first 9,216 B
    const int tid = threadIdx.x;
    const int id  = blockIdx.x;                 // 1024
    const int b   = id & 7;                     // batch-per-XCD heuristic
    const int ho  = id >> 3;
    const int p   = tid & 127;                  // pixel = wo
    const int gh  = tid >> 7;                   // tap group: 0 -> 0..4, 1 -> 4..8
    const int t0  = gh << 2;                    // 0 or 4
    const int lane  = tid & 63;
    const int wv    = tid >> 6;
    const int m     = lane & 31;
    const int kh    = lane >> 5;

    // ================= Phase A: offset conv (M=32, N=128) =================
    {
        const int nbase = wv << 5;
        f32x16 acc = {};
        for (int cc = 0; cc < 4; ++cc) {
            __syncthreads();                    // prev MFMA done with ls
            const unsigned short* xtc = xt + (size_t)(cc * B_ + b) * PLANE * 16;
            bf16x8 af[9];
            #pragma unroll
            for (int ks = 0; ks < 9; ++ks)
                af[ks] = *(const bf16x8*)&wobf[m * KTOT + cc * 144 + ks * 16 + kh * 8];
            #pragma unroll
            for (int i = 0; i < 5; ++i) {
                const int t = t0 + i;
                const int y  = ho - 1 + t / 3;
                const int xx = p  - 1 + t % 3;
                const bool ok = ((unsigned)y < (unsigned)H_) && ((unsigned)xx < (unsigned)W_);
                bf16x8 v0 = {}, v1 = {};
                if (ok) {
                    const unsigned short* rp = xtc + (y * W_ + xx) * 16;
                    v0 = *(const bf16x8*)rp;
                    v1 = *(const bf16x8*)(rp + 8);
                }
                *(bf16x8*)&ls[p * LSTRIDE + t * 16]     = v0;
                *(bf16x8*)&ls[p * LSTRIDE + t * 16 + 8] = v1;
            }
            __syncthreads();                    // ls ready
            #pragma unroll
            for (int ks = 0; ks < 9; ++ks) {
                bf16x8 s = *(const bf16x8*)&ls[(nbase + m) * LSTRIDE + ks * 16 + kh * 8];
                acc = __builtin_amdgcn_mfma_f32_32x32x16_bf16(af[ks], s, acc, 0, 0, 0);
            }
        }
        __syncthreads();                        // all MFMA reads of ls done (lo aliases ls)
        // epilogue -> LDS (D col = pixel nbase+m, row = offset channel)
        #pragma unroll
        for (int r = 0; r < 16; ++r) {
            int mo = (r & 3) + ((r >> 2) << 3) + (kh << 2);
            if (mo < MOFF) lo[mo * 128 + nbase + m] = acc[r] + b_off[mo];
        }
    }
    __syncthreads();                            // lo ready for phase B

    // ================= Phase B: deformable conv (M=64, N=128) =============
    const int mbase = (wv & 1) << 5;
    const int nb0   = (wv >> 1) << 6;           // 0 or 64

    // ---- per-tap sample coords only (10 regs); corners recomputed per chunk
    float py_r[5], px_r[5];
    #pragma unroll
    for (int i = 0; i < 5; ++i) {
        int t = t0 + i;
        py_r[i] = (float)(ho - 1 + t / 3) + lo[(2 * t) * 128 + p];
        px_r[i] = (float)(p  - 1 + t % 3) + lo[(2 * t + 1) * 128 + p];
    }

    f32x16 acc[2] = {};
    for (int cc = 0; cc < 4; ++cc) {
        __syncthreads();                        // lo reads done / prev MFMA done with ls
        const unsigned short* xtc = xt + (size_t)(cc * B_ + b) * PLANE * 16;
        // sampling: 5 taps; corners/weights recomputed (saves 40 VGPRs)
        #pragma unroll
        for (int i = 0; i < 5; ++i) {
            float py = py_r[i], px = px_r[i];
            float fy = floorf(py), fx = floorf(px);
            float wy = py - fy,    wx = px - fx;
            int y0 = (int)fy, x0 = (int)fx;
            float s[16];
            #pragma unroll
            for (int j = 0; j < 16; ++j) s[j] = 0.f;
            #pragma unroll
            for (int c2 = 0; c2 < 4; ++c2) {
                int yy = y0 + (c2 >> 1);
                int xx = x0 + (c2 & 1);
                bool valid = ((unsigned)yy < (unsigned)H_) && ((unsigned)xx < (unsigned)W_);
                int yc = min(max(yy, 0), H_ - 1);
                int xc = min(max(xx, 0), W_ - 1);
                float wgt = ((c2 >> 1) ? wy : 1.f - wy) * ((c2 & 1) ? wx : 1.f - wx);
                wgt = valid ? wgt : 0.f;
                const unsigned short* rp = xtc + (yc * W_ + xc) * 16;
                bf16x8 u0 = *(const bf16x8*)rp;
                bf16x8 u1 = *(const bf16x8*)(rp + 8);
                #pragma unroll
                for (int j = 0; j < 8; ++j) {
                    s[j]     += wgt * bf2f(u0[j]);
                    s[8 + j] += wgt * bf2f(u1[j]);
                }
            }
            bf16x8 v0, v1;
            #pragma unroll
            for (int j = 0; j < 8; ++j) {
                v0[j] = (short)f2bf(s[j]);
                v1[j] = (short)f2bf(s[8 + j]);
            }
            int t = t0 + i;
            *(bf16x8*)&ls[p * LSTRIDE + t * 16]     = v0;
            *(bf16x8*)&ls[p * LSTRIDE + t * 16 + 8] = v1;
        }
        __syncthreads();                        // ls ready
        // MFMA: A-fragments loaded lazily (L2-hot wbf), saves 36 VGPRs
        #pragma unroll
        for (int ks = 0; ks < 9; ++ks) {
            bf16x8 a  = *(const bf16x8*)&wbf[(mbase + m) * KTOT + cc * 144 + ks * 16 + kh * 8];
            bf16x8 s0 = *(const bf16x8*)&ls[(nb0 + m) * LSTRIDE + ks * 16 + kh * 8];
            bf16x8 s1 = *(const bf16x8*)&ls[(nb0 + 32 + m) * LSTRIDE + ks * 16 + kh * 8];
            acc[0] = __builtin_amdgcn_mfma_f32_32x32x16_bf16(a, s0, acc[0], 0, 0, 0);
            acc[1] = __builtin_amdgcn_mfma_f32_32x32x16_bf16(a, s1, acc[1], 0, 0, 0);
        }
    }

    // epilogue: D col = pixel, row = out channel
    #pragma unroll
    for (int nt = 0; nt < 2; ++nt) {
        int col = nb0 + nt * 32 + m;
        float* op = out + (size_t)b * O_ * PLANE + ho * WO_ + col;
        #pragma unroll
        for (int r = 0; r < 16; ++r) {
            int mo = mbase + (r & 3) + ((r >> 2) << 3) + (kh << 2);
            __builtin_nontemporal_store(acc[nt][r] + bias[mo], op + (size_t)mo * PLANE);
        }
    }
}

// ---------------------------------------------------------------------------
extern "C" void kernel_launch(void* const* d_in, const int* in_sizes, int n_in,
                              void* d_out, int out_size, void* d_ws, size_t ws_size,
                              hipStream_t stream) {
    const float* x     = (const float*)d_in[0];
    const float* w_off = (const float*)d_in[1];
    const float* b_off = (const float*)d_in[2];
    const float* w     = (const float*)d_in[3];
    const float* bias  = (const float*)d_in[4];
    float* out = (float*)d_out;

    unsigned short* wbf  = (unsigned short*)d_ws;                   // 72 KB (tap-major)
    unsigned short* wobf = wbf + O_ * KTOT;                         // 36 KB (tap-major)
    unsigned short* xt   = wobf + 32 * KTOT;                        // 16.78 MB chunk-major

    cvt_w_kernel   <<<(O_ * KTOT + 255) / 256, 256, 0, stream>>>(w, wbf);
    cvt_woff_kernel<<<(32 * KTOT + 255) / 256, 256, 0, stream>>>(w_off, wobf);
    nhwc_kernel    <<<B_ * H_, 256, 0, stream>>>(x, xt);
    fused_kernel   <<<B_ * HO_, 256, 0, stream>>>(xt, wobf, b_off, wbf, bias, out);
}